// Round 2
// 169.233 us; speedup vs baseline: 1.1044x; 1.1044x over previous
//
#include <hip/hip_runtime.h>
#include <hip/hip_bf16.h>

namespace {
constexpr int S  = 4096;
constexpr int D  = 768;
constexpr int H  = 12;
constexpr int N3 = 2304;   // 3*D

typedef __bf16 bf16x4 __attribute__((ext_vector_type(4)));
typedef __bf16 bf16x8 __attribute__((ext_vector_type(8)));
typedef float  floatx4 __attribute__((ext_vector_type(4)));

// async global->LDS, 16B per lane; LDS dest = wave-uniform base + lane*16.
__device__ inline void glds16(const __bf16* g, __bf16* l) {
  __builtin_amdgcn_global_load_lds(
      (const __attribute__((address_space(1))) void*)(const void*)g,
      (__attribute__((address_space(3))) void*)(void*)l, 16, 0, 0);
}

// ---------------------------------------------------------------------------
// Kernel 0: merged converts. bid < 3072: x fp32 -> bf16 (1024 elems/block).
// Else: W [768][2304] fp32 -> WT [2304][768] bf16 via LDS tile transpose.
// ---------------------------------------------------------------------------
__global__ __launch_bounds__(256)
void convert_all(const float* __restrict__ x, __bf16* __restrict__ xb,
                 const float* __restrict__ W, __bf16* __restrict__ WT)
{
  const int bid = blockIdx.x;
  const int tid = threadIdx.x;
  if (bid < 3072) {
    const int i = (bid * 256 + tid) * 4;
    floatx4 v = *reinterpret_cast<const floatx4*>(x + i);
    bf16x4 b;
    #pragma unroll
    for (int e = 0; e < 4; ++e) b[e] = (__bf16)v[e];
    *reinterpret_cast<bf16x4*>(xb + i) = b;
  } else {
    __shared__ float T[64][65];
    const int b2 = bid - 3072;
    const int d0 = (b2 % 12) * 64, e0 = (b2 / 12) * 64;
    const int rr = tid >> 4, c4 = (tid & 15) * 4;
    #pragma unroll
    for (int it = 0; it < 4; ++it) {
      int d = it * 16 + rr;
      floatx4 v = *reinterpret_cast<const floatx4*>(W + (d0 + d) * N3 + e0 + c4);
      #pragma unroll
      for (int e = 0; e < 4; ++e) T[d][c4 + e] = v[e];
    }
    __syncthreads();
    #pragma unroll
    for (int it = 0; it < 4; ++it) {
      int e = it * 16 + rr;
      bf16x4 b;
      #pragma unroll
      for (int i = 0; i < 4; ++i) b[i] = (__bf16)T[c4 + i][e];
      *reinterpret_cast<bf16x4*>(WT + (e0 + e) * D + d0 + c4) = b;
    }
  }
}

// ---------------------------------------------------------------------------
// Kernel 1 (VERBATIM): QKV GEMM, 128x96 tile, grid 32x24 = 768 = 3/CU.
// glds16 + XOR swizzle, BK=64. Q/K direct stores; V via swizzled-LDS
// transpose (k-slot-permuted) then coalesced 16B vT stores.
// ---------------------------------------------------------------------------
__global__ __launch_bounds__(256)
void qkv_gemm(const __bf16* __restrict__ xb, const __bf16* __restrict__ WT,
              const float* __restrict__ bq, __bf16* __restrict__ Qb,
              __bf16* __restrict__ Kb, __bf16* __restrict__ vT)
{
  __shared__ __bf16 smem[14336];           // 28 KB: As(16K) | Bs(12K); vts(24K)
  __bf16* As = smem;                        // [128][64] swizzled
  __bf16* Bs = smem + 8192;                 // [96][64]  swizzled

  const int tid  = threadIdx.x;
  const int wave = tid >> 6, lane = tid & 63;
  const int quad = lane >> 4, l16 = lane & 15;
  const int m_base = (wave >> 1) * 64;
  const int n_base = (wave & 1) * 48;
  const int bm = blockIdx.x, bn = blockIdx.y;
  const int srow = lane >> 3, sg = lane & 7;

  floatx4 acc[4][3];
  #pragma unroll
  for (int i = 0; i < 4; ++i)
    #pragma unroll
    for (int j = 0; j < 3; ++j) acc[i][j] = (floatx4){0.f, 0.f, 0.f, 0.f};

  for (int ks = 0; ks < 12; ++ks) {
    const int k0 = ks * 64;
    __syncthreads();
    #pragma unroll
    for (int it = 0; it < 4; ++it) {
      int rbase = it * 32 + wave * 8;
      int row = rbase + srow;
      glds16(xb + (size_t)(bm * 128 + row) * D + k0 + (sg ^ (row & 7)) * 8,
             As + rbase * 64);
    }
    #pragma unroll
    for (int it = 0; it < 3; ++it) {
      int rbase = it * 32 + wave * 8;
      int row = rbase + srow;
      glds16(WT + (size_t)(bn * 96 + row) * D + k0 + (sg ^ (row & 7)) * 8,
             Bs + rbase * 64);
    }
    __syncthreads();

    bf16x8 af[4][2], bfr[3][2];
    #pragma unroll
    for (int mt = 0; mt < 4; ++mt)
      #pragma unroll
      for (int kt = 0; kt < 2; ++kt) {
        int m = m_base + mt * 16 + l16;
        af[mt][kt] = *reinterpret_cast<const bf16x8*>(
            &As[m * 64 + ((((kt << 2) | quad) ^ (l16 & 7)) << 3)]);
      }
    #pragma unroll
    for (int nt = 0; nt < 3; ++nt)
      #pragma unroll
      for (int kt = 0; kt < 2; ++kt) {
        int n = n_base + nt * 16 + l16;
        bfr[nt][kt] = *reinterpret_cast<const bf16x8*>(
            &Bs[n * 64 + ((((kt << 2) | quad) ^ (l16 & 7)) << 3)]);
      }
    #pragma unroll
    for (int kt = 0; kt < 2; ++kt)
      #pragma unroll
      for (int mt = 0; mt < 4; ++mt)
        #pragma unroll
        for (int nt = 0; nt < 3; ++nt)
          acc[mt][nt] = __builtin_amdgcn_mfma_f32_16x16x32_bf16(
              af[mt][kt], bfr[nt][kt], acc[mt][nt], 0, 0, 0);
  }

  if (bn < 16) {
    #pragma unroll
    for (int nt = 0; nt < 3; ++nt) {
      int col = bn * 96 + n_base + nt * 16 + l16;
      float bias = bq[col];
      #pragma unroll
      for (int mt = 0; mt < 4; ++mt) {
        int row = bm * 128 + m_base + mt * 16 + quad * 4;
        #pragma unroll
        for (int r = 0; r < 4; ++r) {
          __bf16 v = (__bf16)(acc[mt][nt][r] + bias);
          if (bn < 8) Qb[(row + r) * D + col] = v;
          else        Kb[(row + r) * D + (col - D)] = v;
        }
      }
    }
  } else {
    __syncthreads();
    __bf16* vts = smem;   // [w 96][t 128], addr = w*128 + (pos ^ ((w&7)<<3))
    #pragma unroll
    for (int nt = 0; nt < 3; ++nt) {
      int wl = n_base + nt * 16 + l16;
      float bias = bq[bn * 96 + wl];
      int sw = (wl & 7) << 3;
      #pragma unroll
      for (int mt = 0; mt < 4; ++mt) {
        #pragma unroll
        for (int r = 0; r < 4; ++r) {
          int tl = m_base + mt * 16 + quad * 4 + r;
          int pos = (tl & ~31) | (quad << 3) | ((tl & 16) >> 2) | r;
          vts[wl * 128 + (pos ^ sw)] = (__bf16)(acc[mt][nt][r] + bias);
        }
      }
    }
    __syncthreads();
    const int w0g = bn * 96 - 2 * D;
    #pragma unroll
    for (int it = 0; it < 6; ++it) {
      int c = it * 256 + tid;
      int wl = c >> 4, t0 = (c & 15) * 8;
      bf16x8 v = *reinterpret_cast<const bf16x8*>(
          &vts[wl * 128 + (t0 ^ ((wl & 7) << 3))]);
      *reinterpret_cast<bf16x8*>(
          &vT[(size_t)(w0g + wl) * S + bm * 128 + t0]) = v;
    }
  }
}

// ---------------------------------------------------------------------------
// Kernel 2: flash attention, pipelined.
//  (a) Ping-pong K LDS buffer + raw s_barrier + counted vmcnt: K(j+1) issued
//      right after B1 (in flight across whole step), V(j+1) issued after the
//      PV-read barrier (in flight across next QK+softmax). No vmcnt(0) drain
//      inside the loop -> DMA latency hidden under compute.
//  (b) Softmax VALU cut: p = exp2(fma(s, 0.125*log2e, (m-1)*10000*log2e))
//      (1 fma + 1 v_exp per element); softmax denominator l via 4 extra
//      MFMAs/step with all-ones A operand (replaces 32 v_add + shfl chain).
//  LDS: Ks0|Ks1 (16K each) + Vt (16K) + Ll (256B) = 49408 B -> 3 blocks/CU.
//  Ping-pong base is computed by offset arithmetic (smem + ((j&1)<<14)) --
//  an ARRAY of LDS-derived pointers does not compile on gfx950.
//  vmcnt bookkeeping per wave per iter (issue order = program order, pinned
//  by asm memory clobbers + sched_barrier):
//    entering iter j: K(j) 4 (oldest), V(j) 4, then mask(j) 4 issued at top
//      -> vmcnt(8) drains K(j).  B1.  issue K(j+1) 4.
//    QK phase: compiler's mask-use wait drains V(j) (older than mask),
//      leaves K(j+1) in flight; explicit vmcnt(4) before B_mid guarantees it.
//    B_mid. PV. B2 (Vt readers done). issue V(j+1) 4.
//  Last iter (j=31): no issues; mask-use wait drains everything; the
//  explicit vmcnt(4) is a no-op (0 outstanding). Correct in both regimes.
// ---------------------------------------------------------------------------
__global__ __launch_bounds__(256)
void attention(const __bf16* __restrict__ Qb, const __bf16* __restrict__ Kb,
               const __bf16* __restrict__ vT, const float* __restrict__ mask,
               float* __restrict__ out)
{
  __shared__ char smem[49408];
  __bf16* Vt = (__bf16*)(smem + 32768);       // [64][128], swizzled+permuted-t
  float*  Ll = (float*)(smem + 49152);        // l partials (64 floats)
  float*  Lo = (float*)smem;                  // alias, end-reduction only

  const int tid  = threadIdx.x;
  const int wave = tid >> 6, lane = tid & 63;
  const int quad = lane >> 4, l16 = lane & 15;
  const int qh = wave >> 1;       // q-half
  const int th = wave & 1;        // t-half
  const int qb = blockIdx.x, h = blockIdx.y;
  const int q0 = qb * 64;
  const int qcol = h * 64;
  const int srow = lane >> 3, sg = lane & 7;
  const int vrow = lane >> 4, vs = lane & 15;

  bf16x8 qf[2][2];
  #pragma unroll
  for (int nt = 0; nt < 2; ++nt)
    #pragma unroll
    for (int kt = 0; kt < 2; ++kt)
      qf[nt][kt] = *reinterpret_cast<const bf16x8*>(
          Qb + (q0 + qh * 32 + nt * 16 + l16) * D + qcol + kt * 32 + quad * 8);

  floatx4 accO[4][2];
  #pragma unroll
  for (int wt = 0; wt < 4; ++wt)
    #pragma unroll
    for (int nt = 0; nt < 2; ++nt) accO[wt][nt] = (floatx4){0.f, 0.f, 0.f, 0.f};
  floatx4 accL[2];
  accL[0] = (floatx4){0.f, 0.f, 0.f, 0.f};
  accL[1] = (floatx4){0.f, 0.f, 0.f, 0.f};
  bf16x8 ones;
  #pragma unroll
  for (int e = 0; e < 8; ++e) ones[e] = (__bf16)1.0f;

  auto stageK = [&](int j, __bf16* dst) {
    #pragma unroll
    for (int it = 0; it < 4; ++it) {
      int rbase = it * 32 + wave * 8;
      int t = rbase + srow;
      glds16(Kb + (size_t)(j * 128 + t) * D + qcol + (sg ^ (t & 7)) * 8,
             dst + rbase * 64);
    }
  };
  auto stageV = [&](int j) {
    #pragma unroll
    for (int it = 0; it < 4; ++it) {
      int wbase = it * 16 + wave * 4;
      int w = wbase + vrow;
      glds16(vT + (size_t)(qcol + w) * S + j * 128 + (vs ^ (w & 7)) * 8,
             Vt + wbase * 128);
    }
  };

  // prologue: K(0), V(0) in flight
  stageK(0, (__bf16*)smem);
  stageV(0);

  for (int j = 0; j < 32; ++j) {
    // mask loads for this step (hoisted above the counted wait so the
    // compiler's mask-use wait drains V(j) but not K(j+1))
    floatx4 mv[4];
    #pragma unroll
    for (int mt = 0; mt < 4; ++mt)
      mv[mt] = *reinterpret_cast<const floatx4*>(
          mask + j * 128 + th * 64 + mt * 16 + quad * 4);

    asm volatile("s_waitcnt vmcnt(8)" ::: "memory");   // own K(j) drained
    __builtin_amdgcn_s_barrier();                      // B1: K(j) visible
    __builtin_amdgcn_sched_barrier(0);

    if (j < 31)                                        // prefetch next K
      stageK(j + 1, (__bf16*)(smem + (((j + 1) & 1) << 14)));
    __builtin_amdgcn_sched_barrier(0);

    const __bf16* Kc = (const __bf16*)(smem + ((j & 1) << 14));

    // S^T = K Q^T ; P = exp2(scale*S + mask2) in-register.
    bf16x4 ps[4][2];
    #pragma unroll
    for (int mt = 0; mt < 4; ++mt) {
      int trow = th * 64 + mt * 16 + l16;
      bf16x8 kf[2];
      #pragma unroll
      for (int kt = 0; kt < 2; ++kt)
        kf[kt] = *reinterpret_cast<const bf16x8*>(
            &Kc[trow * 64 + ((((kt << 2) | quad) ^ (l16 & 7)) << 3)]);
      floatx4 am;   // (m-1)*10000*log2e ; exactly 0 when m==1
      #pragma unroll
      for (int r = 0; r < 4; ++r)
        am[r] = fmaf(mv[mt][r], 14426.9504f, -14426.9504f);
      #pragma unroll
      for (int nt = 0; nt < 2; ++nt) {
        floatx4 s = (floatx4){0.f, 0.f, 0.f, 0.f};
        #pragma unroll
        for (int kt = 0; kt < 2; ++kt)
          s = __builtin_amdgcn_mfma_f32_16x16x32_bf16(kf[kt], qf[nt][kt], s, 0, 0, 0);
        #pragma unroll
        for (int r = 0; r < 4; ++r)
          ps[mt][nt][r] = (__bf16)__builtin_amdgcn_exp2f(
              fmaf(s[r], 0.18033688f, am[r]));   // 0.125*log2e
      }
    }

    asm volatile("s_waitcnt vmcnt(4)" ::: "memory");   // V(j) drained; K(j+1) flies
    __builtin_amdgcn_s_barrier();                      // B_mid: V(j) visible
    __builtin_amdgcn_sched_barrier(0);

    // O^T += V^T P^T ; l via ones-MFMA (sums P columns, rows all equal).
    #pragma unroll
    for (int u = 0; u < 2; ++u) {
      bf16x8 pf[2];
      #pragma unroll
      for (int nt = 0; nt < 2; ++nt)
        #pragma unroll
        for (int r = 0; r < 4; ++r) {
          pf[nt][r]     = ps[2 * u][nt][r];
          pf[nt][4 + r] = ps[2 * u + 1][nt][r];
        }
      #pragma unroll
      for (int nt = 0; nt < 2; ++nt)
        accL[nt] = __builtin_amdgcn_mfma_f32_16x16x32_bf16(
            ones, pf[nt], accL[nt], 0, 0, 0);
      #pragma unroll
      for (int wt = 0; wt < 4; ++wt) {
        int w = wt * 16 + l16;
        bf16x8 vf = *reinterpret_cast<const bf16x8*>(
            &Vt[w * 128 + (((th * 8 + u * 4 + quad) ^ (w & 7)) << 3)]);
        #pragma unroll
        for (int nt = 0; nt < 2; ++nt)
          accO[wt][nt] = __builtin_amdgcn_mfma_f32_16x16x32_bf16(
              vf, pf[nt], accO[wt][nt], 0, 0, 0);
      }
    }

    __builtin_amdgcn_s_barrier();                      // B2: Vt readers done
    __builtin_amdgcn_sched_barrier(0);
    if (j < 31) stageV(j + 1);                         // prefetch next V
    __builtin_amdgcn_sched_barrier(0);
  }

  // l for q = nt*16+l16 over this wave's 64 t: all 4 acc rows identical.
  float l_lane[2] = {accL[0][0], accL[1][0]};

  // ---- cross-wave reduction over t-halves ----
  __syncthreads();   // full drain; safe to alias Lo over K buffers
  if (th == 1) {
    float* dst = Lo + qh * (64 * 33);
    #pragma unroll
    for (int wt = 0; wt < 4; ++wt)
      #pragma unroll
      for (int nt = 0; nt < 2; ++nt)
        #pragma unroll
        for (int r = 0; r < 4; ++r)
          dst[(wt * 16 + quad * 4 + r) * 33 + nt * 16 + l16] = accO[wt][nt][r];
    if (quad == 0) {
      #pragma unroll
      for (int nt = 0; nt < 2; ++nt)
        Ll[qh * 32 + nt * 16 + l16] = l_lane[nt];
    }
  }
  __syncthreads();
  if (th == 0) {
    const float* src = Lo + qh * (64 * 33);
    float l_tot[2];
    #pragma unroll
    for (int nt = 0; nt < 2; ++nt)
      l_tot[nt] = l_lane[nt] + Ll[qh * 32 + nt * 16 + l16];
    #pragma unroll
    for (int wt = 0; wt < 4; ++wt)
      #pragma unroll
      for (int nt = 0; nt < 2; ++nt) {
        floatx4 o;
        #pragma unroll
        for (int r = 0; r < 4; ++r)
          o[r] = (accO[wt][nt][r] +
                  src[(wt * 16 + quad * 4 + r) * 33 + nt * 16 + l16]) / l_tot[nt];
        int row = q0 + qh * 32 + nt * 16 + l16;
        int col = qcol + wt * 16 + quad * 4;
        *reinterpret_cast<floatx4*>(&out[row * D + col]) = o;
      }
  }
}

} // namespace

extern "C" void kernel_launch(void* const* d_in, const int* in_sizes, int n_in,
                              void* d_out, int out_size, void* d_ws, size_t ws_size,
                              hipStream_t stream) {
  const float *x = nullptr, *mask = nullptr, *Wq = nullptr, *bq = nullptr;
  for (int i = 0; i < n_in; ++i) {
    switch (in_sizes[i]) {
      case 3145728: x    = (const float*)d_in[i]; break;
      case 4096:    mask = (const float*)d_in[i]; break;
      case 1769472: Wq   = (const float*)d_in[i]; break;
      case 2304:    bq   = (const float*)d_in[i]; break;
      default: break;
    }
  }

  __bf16* xb = (__bf16*)d_out;               // bf16 scratch in d_out
  __bf16* WT = xb + (size_t)S * D;
  __bf16* Qb = (__bf16*)d_ws;
  __bf16* Kb = Qb + (size_t)S * D;
  __bf16* vT = Kb + (size_t)S * D;

  convert_all<<<3072 + 432, 256, 0, stream>>>(x, xb, Wq, WT);
  qkv_gemm   <<<dim3(S / 128, N3 / 96), 256, 0, stream>>>(xb, WT, bq, Qb, Kb, vT);
  attention  <<<dim3(S / 64, H), 256, 0, stream>>>(Qb, Kb, vT, mask, (float*)d_out);
}